// Round 1
// baseline (326.495 us; speedup 1.0000x reference)
//
#include <hip/hip_runtime.h>

typedef __attribute__((ext_vector_type(8))) short bf16x8;
typedef __attribute__((ext_vector_type(4))) float f32x4;

static __device__ __forceinline__ unsigned short f2bf(float f) {
  unsigned u = __builtin_bit_cast(unsigned, f);
  unsigned r = u + 0x7fffu + ((u >> 16) & 1u);
  return (unsigned short)(r >> 16);
}

// ---------------- kprep: W1g = gamma*fw1@out_w, bias_tot, Wcat x-half ----------------
__global__ __launch_bounds__(256) void kprep(
    const float* __restrict__ out_w, const float* __restrict__ out_b,
    const float* __restrict__ fusion_w, const float* __restrict__ fusion_b,
    const float* __restrict__ gamma,
    float* __restrict__ W1g, float* __restrict__ bias_tot,
    unsigned short* __restrict__ Wcat) {
  const int o = blockIdx.x;
  const int c = threadIdx.x;
  const float g = gamma[0];
  float acc = 0.f, bacc = 0.f;
  for (int t = 0; t < 256; ++t) {
    float fw = fusion_w[o*512 + t];
    acc  += fw * out_w[t*256 + c];
    bacc += fw * out_b[t];
  }
  W1g[o*256 + c] = g * acc;
  if (c == 0) bias_tot[o] = g * bacc + fusion_b[o];
  unsigned short w2b = f2bf(fusion_w[o*512 + 256 + c]);
  for (int b = 0; b < 4; ++b)
    Wcat[((size_t)(b*256 + o))*512 + 256 + c] = w2b;
}

// ---------------- k_qkv: dwconv q/k/v, bx=[v;x] bf16 transposed, partial Grams ------
// grid (64 tiles, 8 heads, 4 batch), block 256
__global__ __launch_bounds__(256) void k_qkv(
    const float* __restrict__ x,
    const float* __restrict__ q_w, const float* __restrict__ q_b,
    const float* __restrict__ k_w, const float* __restrict__ k_b,
    const float* __restrict__ v_w, const float* __restrict__ v_b,
    unsigned short* __restrict__ bx,   // [4][16384][512] bf16: cols 0-255 v, 256-511 x
    float* __restrict__ gp)            // [4][8][64][32][32] partial Grams
{
  __shared__ float xs[16][324];              // 16 ch per pass, 18x18 halo
  __shared__ unsigned short qk[2][32][264];  // q/k bf16, pos-padded (264)
  const int t = blockIdx.x, h = blockIdx.y, b = blockIdx.z;
  const int tid = threadIdx.x;
  const int wv = tid >> 6, lane = tid & 63;
  const int ty = t >> 3, tx = t & 7;
  const int y0 = ty*16, x0 = tx*16;
  const int w4 = __builtin_amdgcn_readfirstlane(wv);  // wave-uniform channel group
  const int py = lane >> 2, px0 = (lane & 3) * 4;

  for (int pass = 0; pass < 2; ++pass) {
    const int cbase = h*32 + pass*16;
    // halo load: 16 ch x 18x18, SAME zero padding
    for (int i = tid; i < 16*324; i += 256) {
      int c = i / 324, r = i - c*324;
      int yy = r / 18, xx = r - yy*18;
      int gy = y0 + yy - 1, gx = x0 + xx - 1;
      float val = 0.f;
      if (gy >= 0 && gy < 128 && gx >= 0 && gx < 128)
        val = x[(((size_t)(b*256 + cbase + c))*128 + gy)*128 + gx];
      xs[c][r] = val;
    }
    __syncthreads();

    float vreg[4][4], xreg[4][4];
    #pragma unroll
    for (int j = 0; j < 4; ++j) {
      const int cl = w4*4 + j;        // channel within pass (0..15)
      const int ch = cbase + cl;      // global channel
      float wq[9], wk[9], wvv[9];
      #pragma unroll
      for (int i2 = 0; i2 < 9; ++i2) {
        wq[i2]  = q_w[ch*9 + i2];
        wk[i2]  = k_w[ch*9 + i2];
        wvv[i2] = v_w[ch*9 + i2];
      }
      const float bq = q_b[ch], bk = k_b[ch], bv = v_b[ch];
      float win[3][6];
      #pragma unroll
      for (int r = 0; r < 3; ++r)
        #pragma unroll
        for (int cx = 0; cx < 6; ++cx)
          win[r][cx] = xs[cl][(py + r)*18 + px0 + cx];
      const int ah = pass*16 + cl;    // channel within head (0..31)
      unsigned short qp[4], kp[4];
      #pragma unroll
      for (int px = 0; px < 4; ++px) {
        float aq = bq, ak = bk, av = bv;
        #pragma unroll
        for (int r = 0; r < 3; ++r)
          #pragma unroll
          for (int cx = 0; cx < 3; ++cx) {
            float xv = win[r][px + cx];
            aq += wq[r*3+cx]*xv;
            ak += wk[r*3+cx]*xv;
            av += wvv[r*3+cx]*xv;
          }
        qp[px] = f2bf(aq);
        kp[px] = f2bf(ak);
        vreg[j][px] = av;
        xreg[j][px] = win[1][px + 1];  // x center
      }
      *(ushort4*)&qk[0][ah][lane*4] = make_ushort4(qp[0], qp[1], qp[2], qp[3]);
      *(ushort4*)&qk[1][ah][lane*4] = make_ushort4(kp[0], kp[1], kp[2], kp[3]);
    }
    // transposed global stores: bx[b][n][col], 8B per (pos, 4ch)
    const int colv = h*32 + pass*16 + w4*4;
    #pragma unroll
    for (int px = 0; px < 4; ++px) {
      int n = (y0 + py)*128 + x0 + px0 + px;
      size_t base = ((size_t)b*16384 + n)*512;
      *(ushort4*)&bx[base + colv] =
          make_ushort4(f2bf(vreg[0][px]), f2bf(vreg[1][px]), f2bf(vreg[2][px]), f2bf(vreg[3][px]));
      *(ushort4*)&bx[base + 256 + colv] =
          make_ushort4(f2bf(xreg[0][px]), f2bf(xreg[1][px]), f2bf(xreg[2][px]), f2bf(xreg[3][px]));
    }
    __syncthreads();
  }

  // Gram quadrant per wave: Gram[c][d] += sum_pos q[c,pos]*k[d,pos], K=256
  const int qm = wv >> 1, qn = wv & 1;
  const int lrow = lane & 15, quad = lane >> 4;
  f32x4 acc = {0.f, 0.f, 0.f, 0.f};
  #pragma unroll
  for (int ks = 0; ks < 8; ++ks) {
    bf16x8 a  = *(const bf16x8*)&qk[0][qm*16 + lrow][ks*32 + quad*8];
    bf16x8 bb = *(const bf16x8*)&qk[1][qn*16 + lrow][ks*32 + quad*8];
    acc = __builtin_amdgcn_mfma_f32_16x16x32_bf16(a, bb, acc, 0, 0, 0);
  }
  float* gpb = gp + ((size_t)((b*8 + h)*64 + t))*1024;
  #pragma unroll
  for (int r = 0; r < 4; ++r)
    gpb[(qm*16 + quad*4 + r)*32 + qn*16 + lrow] = acc[r];  // C/D: col=lane&15, row=quad*4+reg
}

// ---------------- k_softmax: reduce partials, temperature, softmax ----------------
// grid (8,4), block 1024 (thread = (c,d))
__global__ __launch_bounds__(1024) void k_softmax(
    const float* __restrict__ gp, const float* __restrict__ temp,
    float* __restrict__ attn) {
  const int h = blockIdx.x, b = blockIdx.y;
  const int tid = threadIdx.x;
  const int c = tid >> 5, d = tid & 31;
  const float* base = gp + ((size_t)((b*8 + h)*64))*1024;
  float s = 0.f;
  for (int t = 0; t < 64; ++t) s += base[t*1024 + tid];
  s *= temp[h];
  __shared__ float ls[32][33];
  ls[c][d] = s;
  __syncthreads();
  float m = -1e30f;
  #pragma unroll
  for (int i = 0; i < 32; ++i) m = fmaxf(m, ls[c][i]);
  __syncthreads();
  float e = __expf(s - m);
  ls[c][d] = e;
  __syncthreads();
  float sum = 0.f;
  #pragma unroll
  for (int i = 0; i < 32; ++i) sum += ls[c][i];
  attn[((size_t)((b*8 + h)*32 + c))*32 + d] = e / sum;
}

// ---------------- k_compose: M_b = W1g @ attn_blockdiag -> Wcat cols 0..255 --------
// grid (256,4), block 256
__global__ __launch_bounds__(256) void k_compose(
    const float* __restrict__ W1g, const float* __restrict__ attn,
    unsigned short* __restrict__ Wcat) {
  const int o = blockIdx.x, b = blockIdx.y;
  const int e = threadIdx.x;
  const int h = e >> 5, d = e & 31;
  const float* ab = attn + ((size_t)((b*8 + h)*32))*32 + d;
  const float* wb = W1g + o*256 + h*32;
  float s = 0.f;
  #pragma unroll
  for (int c2 = 0; c2 < 32; ++c2) s += wb[c2] * ab[c2*32];
  Wcat[((size_t)(b*256 + o))*512 + e] = f2bf(s);
}

// ---------------- k_gemm: out = Wcat[256x512] @ [v;x][512x16384] + bias ------------
// grid (256 n-tiles, 4 batch), block 256 (4 waves), tile M=256 N=64 K=512 BK=32
__global__ __launch_bounds__(256) void k_gemm(
    const unsigned short* __restrict__ Wcat,
    const unsigned short* __restrict__ bx,
    const float* __restrict__ bias_tot,
    float* __restrict__ out) {
  __shared__ unsigned short Al[256][40];  // stride 40 (80B): conflict-free b128 frags
  __shared__ unsigned short Bl[64][40];
  const int nt = blockIdx.x, b = blockIdx.y;
  const int tid = threadIdx.x;
  const int wv = tid >> 6, lane = tid & 63;
  const int lrow = lane & 15, quad = lane >> 4;
  const int nbase = nt * 64;
  const unsigned short* Ab = Wcat + (size_t)b * 256 * 512;
  const unsigned short* Bb = bx + ((size_t)b * 16384 + nbase) * 512;
  f32x4 acc[4][4] = {};

  const int srow = tid >> 2;
  const int sq4 = tid & 3;
  for (int ks = 0; ks < 16; ++ks) {
    const int k0 = ks * 32;
    #pragma unroll
    for (int r = 0; r < 4; ++r) {
      int row = srow + r*64;
      uint4 v4 = *(const uint4*)(Ab + (size_t)row*512 + k0 + sq4*8);
      *(uint4*)&Al[row][sq4*8] = v4;
    }
    {
      uint4 v4 = *(const uint4*)(Bb + (size_t)srow*512 + k0 + sq4*8);
      *(uint4*)&Bl[srow][sq4*8] = v4;
    }
    __syncthreads();
    bf16x8 af[4], bfv[4];
    #pragma unroll
    for (int i = 0; i < 4; ++i)
      af[i] = *(const bf16x8*)&Al[wv*64 + i*16 + lrow][quad*8];
    #pragma unroll
    for (int j = 0; j < 4; ++j)
      bfv[j] = *(const bf16x8*)&Bl[j*16 + lrow][quad*8];
    #pragma unroll
    for (int i = 0; i < 4; ++i)
      #pragma unroll
      for (int j = 0; j < 4; ++j)
        acc[i][j] = __builtin_amdgcn_mfma_f32_16x16x32_bf16(af[i], bfv[j], acc[i][j], 0, 0, 0);
    __syncthreads();
  }
  #pragma unroll
  for (int i = 0; i < 4; ++i) {
    #pragma unroll
    for (int r = 0; r < 4; ++r) {
      const int o = wv*64 + i*16 + quad*4 + r;
      const float bias = bias_tot[o];
      #pragma unroll
      for (int j = 0; j < 4; ++j) {
        const int n = nbase + j*16 + lrow;
        out[((size_t)(b*256 + o))*16384 + n] = acc[i][j][r] + bias;
      }
    }
  }
}

extern "C" void kernel_launch(void* const* d_in, const int* in_sizes, int n_in,
                              void* d_out, int out_size, void* d_ws, size_t ws_size,
                              hipStream_t stream) {
  const float* x        = (const float*)d_in[0];
  const float* q_w      = (const float*)d_in[1];
  const float* q_b      = (const float*)d_in[2];
  const float* k_w      = (const float*)d_in[3];
  const float* k_b      = (const float*)d_in[4];
  const float* v_w      = (const float*)d_in[5];
  const float* v_b      = (const float*)d_in[6];
  const float* out_w    = (const float*)d_in[7];
  const float* out_b    = (const float*)d_in[8];
  const float* fusion_w = (const float*)d_in[9];
  const float* fusion_b = (const float*)d_in[10];
  const float* temp     = (const float*)d_in[11];
  const float* gamma    = (const float*)d_in[12];
  float* out = (float*)d_out;

  char* ws = (char*)d_ws;
  unsigned short* bx   = (unsigned short*)(ws);             // 67,108,864 B
  float* gp            = (float*)(ws + 67108864);           //  8,388,608 B
  float* attn          = (float*)(ws + 75497472);           //    131,072 B
  float* W1g           = (float*)(ws + 75628544);           //    262,144 B
  float* bias_tot      = (float*)(ws + 75890688);           //      1,024 B
  unsigned short* Wcat = (unsigned short*)(ws + 75891712);  //  1,048,576 B (total ~73.4 MB)

  kprep<<<dim3(256), dim3(256), 0, stream>>>(out_w, out_b, fusion_w, fusion_b,
                                             gamma, W1g, bias_tot, Wcat);
  k_qkv<<<dim3(64, 8, 4), dim3(256), 0, stream>>>(x, q_w, q_b, k_w, k_b, v_w, v_b, bx, gp);
  k_softmax<<<dim3(8, 4), dim3(1024), 0, stream>>>(gp, temp, attn);
  k_compose<<<dim3(256, 4), dim3(256), 0, stream>>>(W1g, attn, Wcat);
  k_gemm<<<dim3(256, 4), dim3(256), 0, stream>>>(Wcat, bx, bias_tot, out);
}